// Round 5
// baseline (554.547 us; speedup 1.0000x reference)
//
#include <hip/hip_runtime.h>

#define NN 200000
#define NE 600000
#define DD 128
#define GT 1563   // ceil(NN/128) gemm row tiles

constexpr float BN_EPS = 1e-5f;

typedef unsigned short u16;
typedef short bf16x8 __attribute__((ext_vector_type(8)));
typedef float f32x4  __attribute__((ext_vector_type(4)));
typedef float f32x2  __attribute__((ext_vector_type(2)));

// ---------------- init / degree / stats ----------------

__global__ void k_zero(int* __restrict__ cnt, float* __restrict__ ssum, float* __restrict__ ssq) {
  int i = blockIdx.x*256 + threadIdx.x;
  if (i < NN) cnt[i] = 0;
  if (i < DD) { ssum[i] = 0.f; ssq[i] = 0.f; }
}

__global__ void k_count(const int* __restrict__ ei, int* __restrict__ cnt) {
  int e = blockIdx.x*256 + threadIdx.x;
  if (e < NE) atomicAdd(&cnt[ei[NE + e]], 1);
}

// column sums of prelu(x, a1): ssum[c], ssq[c]
// float4 per lane (16B), 8 row-groups/block, LDS reduce, 1 atomic/col/block.
__global__ void k_stats(const float* __restrict__ x, const float* __restrict__ a1p,
                        float* __restrict__ ssum, float* __restrict__ ssq) {
  __shared__ float s1[8][128], s2[8][128];
  const int c4 = (threadIdx.x & 31) * 4;
  const int rg = threadIdx.x >> 5;
  float a1 = *a1p;
  float acc1[4] = {0.f,0.f,0.f,0.f}, acc2[4] = {0.f,0.f,0.f,0.f};
  const int stride = gridDim.x * 8;
  for (int r = blockIdx.x*8 + rg; r < NN; r += stride) {
    float4 v = *(const float4*)(x + (size_t)r*DD + c4);
    float vv[4] = {v.x, v.y, v.z, v.w};
    #pragma unroll
    for (int i = 0; i < 4; ++i) {
      float u = vv[i];
      u = (u >= 0.f) ? u : a1*u;
      acc1[i] += u; acc2[i] += u*u;
    }
  }
  *(float4*)&s1[rg][c4] = make_float4(acc1[0], acc1[1], acc1[2], acc1[3]);
  *(float4*)&s2[rg][c4] = make_float4(acc2[0], acc2[1], acc2[2], acc2[3]);
  __syncthreads();
  if (threadIdx.x < 128) {
    int col = threadIdx.x;
    float t1 = 0.f, t2 = 0.f;
    #pragma unroll
    for (int g = 0; g < 8; ++g) { t1 += s1[g][col]; t2 += s2[g][col]; }
    atomicAdd(&ssum[col], t1);
    atomicAdd(&ssq [col], t2);
  }
}

// BN params s,t and tw1[j] = sum_k t[k] * W1[k,j]   (single block, 128 threads)
__global__ void k_bn_tw1(const float* __restrict__ ssum, const float* __restrict__ ssq,
                         const float* __restrict__ gamma, const float* __restrict__ beta,
                         const float* __restrict__ W1,
                         float* __restrict__ sarr, float* __restrict__ tarr,
                         float* __restrict__ tw1) {
  __shared__ float ts[128];
  int j = threadIdx.x;
  float mean = ssum[j] * (1.f/NN);
  float var  = ssq[j] * (1.f/NN) - mean*mean;
  float s = gamma[j] * rsqrtf(var + BN_EPS);
  float t = beta[j] - mean*s;
  sarr[j] = s; tarr[j] = t; ts[j] = t;
  __syncthreads();
  float acc = 0.f;
  #pragma unroll 8
  for (int k = 0; k < 128; ++k) acc += ts[k] * W1[k*DD + j];
  tw1[j] = acc;
}

// W prep: Wt[j][k] = (s ? s[k] : 1) * W[k][j], split into bf16 hi/lo (truncation).
// 16384 elements, grid 64 x 256.
__global__ void k_wprep(const float* __restrict__ W, const float* __restrict__ s,
                        u16* __restrict__ hi, u16* __restrict__ lo) {
  int idx = blockIdx.x*256 + threadIdx.x;
  int j = idx >> 7, k = idx & 127;
  float v = W[(size_t)k*DD + j];
  if (s) v *= s[k];
  unsigned hb = __float_as_uint(v) & 0xffff0000u;
  float r = v - __uint_as_float(hb);           // exact residual
  hi[idx] = (u16)(hb >> 16);
  lo[idx] = (u16)(__float_as_uint(r) >> 16);
}

// ---------------- exclusive scan (3 pass) ----------------

__global__ void k_scan1(const int* __restrict__ cnt, int* __restrict__ rp, int* __restrict__ bsums) {
  __shared__ int sm[256];
  int tid = threadIdx.x;
  int base = blockIdx.x*1024 + tid*4;
  int4 v = make_int4(0,0,0,0);
  if (base + 3 < NN) v = *(const int4*)(cnt + base);
  else {
    if (base   < NN) v.x = cnt[base];
    if (base+1 < NN) v.y = cnt[base+1];
    if (base+2 < NN) v.z = cnt[base+2];
    if (base+3 < NN) v.w = cnt[base+3];
  }
  int p1 = v.x, p2 = p1 + v.y, p3 = p2 + v.z, tsum = p3 + v.w;
  sm[tid] = tsum; __syncthreads();
  for (int off = 1; off < 256; off <<= 1) {
    int t = (tid >= off) ? sm[tid - off] : 0; __syncthreads();
    sm[tid] += t; __syncthreads();
  }
  int inc = sm[tid];
  int excl = inc - tsum;
  if (base   < NN) rp[base]   = excl;
  if (base+1 < NN) rp[base+1] = excl + p1;
  if (base+2 < NN) rp[base+2] = excl + p2;
  if (base+3 < NN) rp[base+3] = excl + p3;
  if (tid == 255) bsums[blockIdx.x] = inc;
}

__global__ void k_scan2(int* __restrict__ bsums, int nb) {
  __shared__ int sm[256];
  int tid = threadIdx.x;
  int v = (tid < nb) ? bsums[tid] : 0;
  sm[tid] = v; __syncthreads();
  for (int off = 1; off < 256; off <<= 1) {
    int t = (tid >= off) ? sm[tid - off] : 0; __syncthreads();
    sm[tid] += t; __syncthreads();
  }
  if (tid < nb) bsums[tid] = sm[tid] - v;   // exclusive
}

// fused: finalize row pointers + cur + dinv
__global__ void k_scan3(int* __restrict__ rp, const int* __restrict__ bsums,
                        int* __restrict__ cur, const int* __restrict__ cnt,
                        float* __restrict__ dinv) {
  int i = blockIdx.x*256 + threadIdx.x;
  if (i < NN) {
    int val = rp[i] + bsums[i >> 10];
    rp[i] = val; cur[i] = val;
    dinv[i] = rsqrtf((float)(cnt[i] + 1));
  }
  if (i == 0) rp[NN] = NE;
}

__global__ void k_fill(const int* __restrict__ ei, const float* __restrict__ dinv,
                       int* __restrict__ cur, int2* __restrict__ pairs) {
  int e = blockIdx.x*256 + threadIdx.x;
  if (e < NE) {
    int s = ei[e], d = ei[NE + e];
    int pos = atomicAdd(&cur[d], 1);
    float cf = dinv[s] * dinv[d];
    pairs[pos] = make_int2(s, __float_as_int(cf));
  }
}

// ---------------- GEMM: C[N,128] = prelu(A)[N,128] @ W'[128,128] (+ row add) ----------------
// MFMA bf16x3 split-precision: A = Ah+Al, W' = Wh+Wl (pre-split, transposed, BN scale
// folded into W1). acc += Ah*Wh + Ah*Wl + Al*Wh  -> ~fp32 accuracy at MFMA rate.

template<bool FUSE, bool ADDROW>
__global__ __launch_bounds__(256)
void k_gemm(const float* __restrict__ A,
            const u16* __restrict__ wt_hi, const u16* __restrict__ wt_lo,
            float* __restrict__ C,
            const float* __restrict__ tw1, const float* __restrict__ a1p)
{
  __shared__ u16 Bh[128][136];
  __shared__ u16 Bl[128][136];
  const int tid = threadIdx.x;

  // stage Wt hi/lo: 2048 16B chunks each, 8 per thread
  #pragma unroll
  for (int i = 0; i < 8; ++i) {
    int c = tid + i*256;
    int row = c >> 4, slot = c & 15;
    *(uint4*)&Bh[row][slot*8] = ((const uint4*)wt_hi)[c];
    *(uint4*)&Bl[row][slot*8] = ((const uint4*)wt_lo)[c];
  }

  float a1v = 0.f;
  if constexpr (FUSE) a1v = *a1p;

  const int lane = tid & 63;
  const int wv   = tid >> 6;            // wave 0..3
  const int lr   = lane & 15;           // A row within strip / C col within tile
  const int lk   = lane >> 4;           // k sub-block 0..3
  const int r0   = blockIdx.x*128 + wv*32;

  f32x4 acc[2][8];
  #pragma unroll
  for (int s = 0; s < 2; ++s)
    #pragma unroll
    for (int j = 0; j < 8; ++j) acc[s][j] = (f32x4){0.f,0.f,0.f,0.f};

  __syncthreads();

  #pragma unroll
  for (int kc = 0; kc < 4; ++kc) {
    bf16x8 ah[2], al[2];
    #pragma unroll
    for (int s = 0; s < 2; ++s) {
      int r = r0 + s*16 + lr; r = (r < NN) ? r : (NN-1);
      const float* ap = A + (size_t)r*DD + kc*32 + lk*8;
      float4 v0 = *(const float4*)ap;
      float4 v1 = *(const float4*)(ap + 4);
      float vv[8] = {v0.x,v0.y,v0.z,v0.w,v1.x,v1.y,v1.z,v1.w};
      #pragma unroll
      for (int e = 0; e < 8; ++e) {
        float v = vv[e];
        if constexpr (FUSE) v = (v >= 0.f) ? v : a1v*v;
        unsigned hb = __float_as_uint(v) & 0xffff0000u;
        float rres = v - __uint_as_float(hb);    // exact
        ah[s][e] = (short)(hb >> 16);
        al[s][e] = (short)(__float_as_uint(rres) >> 16);
      }
    }
    #pragma unroll
    for (int j = 0; j < 8; ++j) {
      int wrow = j*16 + lr;
      bf16x8 bh = *(const bf16x8*)&Bh[wrow][kc*32 + lk*8];
      bf16x8 bl = *(const bf16x8*)&Bl[wrow][kc*32 + lk*8];
      #pragma unroll
      for (int s = 0; s < 2; ++s) {
        acc[s][j] = __builtin_amdgcn_mfma_f32_16x16x32_bf16(ah[s], bh, acc[s][j], 0, 0, 0);
        acc[s][j] = __builtin_amdgcn_mfma_f32_16x16x32_bf16(ah[s], bl, acc[s][j], 0, 0, 0);
        acc[s][j] = __builtin_amdgcn_mfma_f32_16x16x32_bf16(al[s], bh, acc[s][j], 0, 0, 0);
      }
    }
  }

  float tw[8];
  #pragma unroll
  for (int j = 0; j < 8; ++j) tw[j] = 0.f;
  if constexpr (ADDROW) {
    #pragma unroll
    for (int j = 0; j < 8; ++j) tw[j] = tw1[j*16 + lr];
  }

  // C/D layout (m89): col = lane&15, row = (lane>>4)*4 + reg
  #pragma unroll
  for (int s = 0; s < 2; ++s) {
    #pragma unroll
    for (int g = 0; g < 4; ++g) {
      int row = r0 + s*16 + lk*4 + g;
      if (row < NN) {
        float* cp = C + (size_t)row*DD + lr;
        #pragma unroll
        for (int j = 0; j < 8; ++j) cp[j*16] = acc[s][j][g] + tw[j];
      }
    }
  }
}

// ---------------- fused agg1 + gemm2 ----------------
// Per wave: 16 nodes. Lane l owns node (l&15) and feature slice q=(l>>4):
// features f = kc*32 + q*8 + e. After aggregation the result sits in registers
// in EXACTLY the MFMA B-fragment layout (B[k][col=node]); W2t hi/lo planes load
// in exactly the A-fragment layout (A[row=j][k], row=lane&15). No LDS, no sync.
// D[j][node]: col=lane&15=node, row=(lane>>4)*4+reg=j -> coalesced float4 store.

__global__ __launch_bounds__(256)
void k_aggmm(const float* __restrict__ h, const int* __restrict__ rp,
             const int2* __restrict__ pairs,
             const u16* __restrict__ wt_hi, const u16* __restrict__ wt_lo,
             const float* __restrict__ b1, const float* __restrict__ a2p,
             float* __restrict__ A2)
{
  const int lane = threadIdx.x & 63;
  const int wave = threadIdx.x >> 6;
  const int nb   = (blockIdx.x*4 + wave) * 16;
  const int nd   = lane & 15;
  const int q    = lane >> 4;
  const int node = nb + nd;

  int rv = 0;
  if (lane < 17) rv = rp[nb + lane];
  int beg = __shfl(rv, nd);
  int cnt = __shfl(rv, nd + 1) - beg;

  // wave-max of cnt (cnt depends only on low 4 lane bits)
  int mc = cnt;
  #pragma unroll
  for (int off = 1; off < 16; off <<= 1)
    mc = max(mc, __shfl_xor(mc, off));

  // acc[kc][e] over my 32 features; init = self*1/(deg) + b1
  float acc[4][8];
  {
    float sc = 1.f / (float)(cnt + 1);
    const float* hp = h + (size_t)node*DD + q*8;
    const float* bp = b1 + q*8;
    #pragma unroll
    for (int kc = 0; kc < 4; ++kc) {
      float4 s0 = *(const float4*)(hp + kc*32);
      float4 s1 = *(const float4*)(hp + kc*32 + 4);
      float4 w0 = *(const float4*)(bp + kc*32);
      float4 w1 = *(const float4*)(bp + kc*32 + 4);
      acc[kc][0] = sc*s0.x + w0.x; acc[kc][1] = sc*s0.y + w0.y;
      acc[kc][2] = sc*s0.z + w0.z; acc[kc][3] = sc*s0.w + w0.w;
      acc[kc][4] = sc*s1.x + w1.x; acc[kc][5] = sc*s1.y + w1.y;
      acc[kc][6] = sc*s1.z + w1.z; acc[kc][7] = sc*s1.w + w1.w;
    }
  }

  const int2* pb = pairs + beg;
  for (int c = 0; c < mc; ++c) {
    if (c < cnt) {            // exec-masked: inactive lanes issue no loads
      int2 p = pb[c];
      float cf = __int_as_float(p.y);
      const float* gp = h + (size_t)p.x*DD + q*8;
      #pragma unroll
      for (int kc = 0; kc < 4; ++kc) {
        float4 g0 = *(const float4*)(gp + kc*32);
        float4 g1 = *(const float4*)(gp + kc*32 + 4);
        acc[kc][0] += cf*g0.x; acc[kc][1] += cf*g0.y;
        acc[kc][2] += cf*g0.z; acc[kc][3] += cf*g0.w;
        acc[kc][4] += cf*g1.x; acc[kc][5] += cf*g1.y;
        acc[kc][6] += cf*g1.z; acc[kc][7] += cf*g1.w;
      }
    }
  }

  // prelu(a2) + bf16 hi/lo split -> B-fragments
  float a2 = *a2p;
  bf16x8 bh[4], bl[4];
  #pragma unroll
  for (int kc = 0; kc < 4; ++kc)
    #pragma unroll
    for (int e = 0; e < 8; ++e) {
      float v = acc[kc][e];
      v = (v >= 0.f) ? v : a2*v;
      unsigned hb = __float_as_uint(v) & 0xffff0000u;
      float r = v - __uint_as_float(hb);
      bh[kc][e] = (short)(hb >> 16);
      bl[kc][e] = (short)(__float_as_uint(r) >> 16);
    }

  // gemm: D[j][node] = sum_k W2t[j][k] * g[node][k], bf16x3
  float* op = A2 + (size_t)node*DD + q*4;
  const u16* whB = wt_hi + (size_t)nd*DD + q*8;
  const u16* wlB = wt_lo + (size_t)nd*DD + q*8;
  #pragma unroll
  for (int jt = 0; jt < 8; ++jt) {
    f32x4 d = (f32x4){0.f,0.f,0.f,0.f};
    const u16* wh = whB + (size_t)jt*16*DD;
    const u16* wl = wlB + (size_t)jt*16*DD;
    #pragma unroll
    for (int kc = 0; kc < 4; ++kc) {
      bf16x8 ah = *(const bf16x8*)(wh + kc*32);
      bf16x8 al = *(const bf16x8*)(wl + kc*32);
      d = __builtin_amdgcn_mfma_f32_16x16x32_bf16(ah, bh[kc], d, 0, 0, 0);
      d = __builtin_amdgcn_mfma_f32_16x16x32_bf16(ah, bl[kc], d, 0, 0, 0);
      d = __builtin_amdgcn_mfma_f32_16x16x32_bf16(al, bh[kc], d, 0, 0, 0);
    }
    *(float4*)(op + jt*16) = make_float4(d[0], d[1], d[2], d[3]);
  }
}

// ---------------- aggregation: 8 nodes per wave, interleaved gathers ----------------

template<bool PRELU>
__global__ __launch_bounds__(256)
void k_agg(const float* __restrict__ h, const int* __restrict__ rp,
           const int2* __restrict__ pairs,
           const float* __restrict__ bias, const float* __restrict__ a2p,
           float* __restrict__ out)
{
  const int wave = threadIdx.x >> 6;
  const int lane = threadIdx.x & 63;
  const int nb = (blockIdx.x*4 + wave) * 8;
  if (nb >= NN) return;
  const float2* h2 = (const float2*)h;
  f32x2* o2 = (f32x2*)out;

  int rv = 0;
  if (lane < 9) rv = rp[nb + lane];
  int beg[8], cnt8[8];
  #pragma unroll
  for (int i = 0; i < 8; ++i) {
    int b0 = __builtin_amdgcn_readfirstlane(__shfl(rv, i));
    int b1 = __builtin_amdgcn_readfirstlane(__shfl(rv, i+1));
    beg[i] = b0; cnt8[i] = b1 - b0;
  }

  float2 b = ((const float2*)bias)[lane];
  float a2 = 1.f;
  if constexpr (PRELU) a2 = *a2p;

  float2 acc[8];
  #pragma unroll
  for (int i = 0; i < 8; ++i) {
    float2 self = h2[(size_t)(nb+i)*64 + lane];
    float sc = 1.f / (float)(cnt8[i] + 1);     // dinv^2 exactly
    acc[i].x = sc*self.x + b.x;
    acc[i].y = sc*self.y + b.y;
  }

  int maxc = 0;
  #pragma unroll
  for (int i = 0; i < 8; ++i) maxc = max(maxc, cnt8[i]);

  for (int c = 0; c < maxc; ++c) {
    int2 p[8];
    #pragma unroll
    for (int i = 0; i < 8; ++i)
      if (c < cnt8[i]) p[i] = pairs[beg[i] + c];
    #pragma unroll
    for (int i = 0; i < 8; ++i)
      if (c < cnt8[i]) {
        float2 g = h2[(size_t)p[i].x*64 + lane];
        float cf = __int_as_float(p[i].y);
        acc[i].x += cf*g.x; acc[i].y += cf*g.y;
      }
  }

  #pragma unroll
  for (int i = 0; i < 8; ++i) {
    float ax = acc[i].x, ay = acc[i].y;
    if constexpr (PRELU) {
      ax = (ax >= 0.f) ? ax : a2*ax;
      ay = (ay >= 0.f) ? ay : a2*ay;
    }
    f32x2 o; o[0] = ax; o[1] = ay;
    __builtin_nontemporal_store(o, &o2[(size_t)(nb+i)*64 + lane]);
  }
}

// ---------------- launch ----------------

extern "C" void kernel_launch(void* const* d_in, const int* in_sizes, int n_in,
                              void* d_out, int out_size, void* d_ws, size_t ws_size,
                              hipStream_t stream) {
  const float* x     = (const float*)d_in[0];
  const int*   ei    = (const int*)  d_in[1];
  const float* a1    = (const float*)d_in[2];
  const float* gamma = (const float*)d_in[3];
  const float* beta  = (const float*)d_in[4];
  const float* W1    = (const float*)d_in[5];
  const float* b1    = (const float*)d_in[6];
  const float* a2    = (const float*)d_in[7];
  const float* W2    = (const float*)d_in[8];
  const float* b2    = (const float*)d_in[9];
  float* out = (float*)d_out;

  char* w = (char*)d_ws;
  auto alloc = [&](size_t bytes) { char* p = w; w += (bytes + 255) & ~(size_t)255; return p; };
  float* hbuf  = (float*)alloc((size_t)NN*DD*4);   // 102.4 MB
  float* dinv  = (float*)alloc((size_t)NN*4);
  int*   cnt   = (int*)  alloc((size_t)NN*4);
  int*   rp    = (int*)  alloc((size_t)(NN+1)*4);
  int*   cur   = (int*)  alloc((size_t)NN*4);
  int2*  pairs = (int2*) alloc((size_t)NE*8);
  int*   bsums = (int*)  alloc(256*4);
  float* ssum  = (float*)alloc(128*4);
  float* ssq   = (float*)alloc(128*4);
  float* sarr  = (float*)alloc(128*4);
  float* tarr  = (float*)alloc(128*4);
  float* tw1   = (float*)alloc(128*4);
  u16*   w1h   = (u16*)  alloc(128*128*2);
  u16*   w1l   = (u16*)  alloc(128*128*2);
  u16*   w2h   = (u16*)  alloc(128*128*2);
  u16*   w2l   = (u16*)  alloc(128*128*2);
  float* hbuf2 = (float*)alloc((size_t)NN*DD*4);   // 102.4 MB (fused path only)
  const bool fused = ((size_t)(w - (char*)d_ws) <= ws_size);

  const int nblkN = (NN + 255)/256;
  const int nblkE = (NE + 255)/256;
  const int nblkA = NN/32;   // 8 nodes/wave * 4 waves/block
  const int nblkF = NN/64;   // 16 nodes/wave * 4 waves/block

  k_zero  <<<nblkN, 256, 0, stream>>>(cnt, ssum, ssq);
  k_count <<<nblkE, 256, 0, stream>>>(ei, cnt);
  k_stats <<<1024,  256, 0, stream>>>(x, a1, ssum, ssq);
  k_bn_tw1<<<1,     128, 0, stream>>>(ssum, ssq, gamma, beta, W1, sarr, tarr, tw1);
  k_wprep <<<64,    256, 0, stream>>>(W2, nullptr, w2h, w2l);
  k_wprep <<<64,    256, 0, stream>>>(W1, sarr,    w1h, w1l);
  k_scan1 <<<196,   256, 0, stream>>>(cnt, rp, bsums);
  k_scan2 <<<1,     256, 0, stream>>>(bsums, 196);
  k_scan3 <<<nblkN, 256, 0, stream>>>(rp, bsums, cur, cnt, dinv);
  k_fill  <<<nblkE, 256, 0, stream>>>(ei, dinv, cur, pairs);

  k_gemm<true, true><<<GT, 256, 0, stream>>>(x, w1h, w1l, hbuf, tw1, a1);
  if (fused) {
    // agg1 + gemm2 fused: hbuf -> hbuf2 (dense pre-aggregation activations)
    k_aggmm<<<nblkF, 256, 0, stream>>>(hbuf, rp, pairs, w2h, w2l, b1, a2, hbuf2);
    k_agg<false><<<nblkA, 256, 0, stream>>>(hbuf2, rp, pairs, b2, nullptr, out);
  } else {
    k_agg<true >         <<<nblkA, 256, 0, stream>>>(hbuf, rp, pairs, b1, a2, out);
    k_gemm<false, false><<<GT, 256, 0, stream>>>(out, w2h, w2l, hbuf, nullptr, nullptr);
    k_agg<false>         <<<nblkA, 256, 0, stream>>>(hbuf, rp, pairs, b2, nullptr, out);
  }
}

// Round 6
// 515.910 us; speedup vs baseline: 1.0749x; 1.0749x over previous
//
#include <hip/hip_runtime.h>

#define NN 200000
#define NE 600000
#define DD 128
#define GT 1563   // ceil(NN/128) gemm row tiles

constexpr float BN_EPS = 1e-5f;

typedef unsigned short u16;
typedef short bf16x8 __attribute__((ext_vector_type(8)));
typedef float f32x4  __attribute__((ext_vector_type(4)));
typedef float f32x2  __attribute__((ext_vector_type(2)));

// ---------------- init / degree / stats ----------------

__global__ void k_zero(int* __restrict__ cnt, float* __restrict__ ssum, float* __restrict__ ssq) {
  int i = blockIdx.x*256 + threadIdx.x;
  if (i < NN) cnt[i] = 0;
  if (i < DD) { ssum[i] = 0.f; ssq[i] = 0.f; }
}

__global__ void k_count(const int* __restrict__ ei, int* __restrict__ cnt) {
  int e = blockIdx.x*256 + threadIdx.x;
  if (e < NE) atomicAdd(&cnt[ei[NE + e]], 1);
}

// column sums of prelu(x, a1): ssum[c], ssq[c]
// float4 per lane (16B), 8 row-groups/block, LDS reduce, 1 atomic/col/block.
__global__ void k_stats(const float* __restrict__ x, const float* __restrict__ a1p,
                        float* __restrict__ ssum, float* __restrict__ ssq) {
  __shared__ float s1[8][128], s2[8][128];
  const int c4 = (threadIdx.x & 31) * 4;
  const int rg = threadIdx.x >> 5;
  float a1 = *a1p;
  float acc1[4] = {0.f,0.f,0.f,0.f}, acc2[4] = {0.f,0.f,0.f,0.f};
  const int stride = gridDim.x * 8;
  for (int r = blockIdx.x*8 + rg; r < NN; r += stride) {
    float4 v = *(const float4*)(x + (size_t)r*DD + c4);
    float vv[4] = {v.x, v.y, v.z, v.w};
    #pragma unroll
    for (int i = 0; i < 4; ++i) {
      float u = vv[i];
      u = (u >= 0.f) ? u : a1*u;
      acc1[i] += u; acc2[i] += u*u;
    }
  }
  *(float4*)&s1[rg][c4] = make_float4(acc1[0], acc1[1], acc1[2], acc1[3]);
  *(float4*)&s2[rg][c4] = make_float4(acc2[0], acc2[1], acc2[2], acc2[3]);
  __syncthreads();
  if (threadIdx.x < 128) {
    int col = threadIdx.x;
    float t1 = 0.f, t2 = 0.f;
    #pragma unroll
    for (int g = 0; g < 8; ++g) { t1 += s1[g][col]; t2 += s2[g][col]; }
    atomicAdd(&ssum[col], t1);
    atomicAdd(&ssq [col], t2);
  }
}

// BN params s,t and tw1[j] = sum_k t[k] * W1[k,j]   (single block, 128 threads)
__global__ void k_bn_tw1(const float* __restrict__ ssum, const float* __restrict__ ssq,
                         const float* __restrict__ gamma, const float* __restrict__ beta,
                         const float* __restrict__ W1,
                         float* __restrict__ sarr, float* __restrict__ tarr,
                         float* __restrict__ tw1) {
  __shared__ float ts[128];
  int j = threadIdx.x;
  float mean = ssum[j] * (1.f/NN);
  float var  = ssq[j] * (1.f/NN) - mean*mean;
  float s = gamma[j] * rsqrtf(var + BN_EPS);
  float t = beta[j] - mean*s;
  sarr[j] = s; tarr[j] = t; ts[j] = t;
  __syncthreads();
  float acc = 0.f;
  #pragma unroll 8
  for (int k = 0; k < 128; ++k) acc += ts[k] * W1[k*DD + j];
  tw1[j] = acc;
}

// W prep: Wt[j][k] = (s ? s[k] : 1) * W[k][j], split into bf16 hi/lo (truncation).
// 16384 elements, grid 64 x 256.
__global__ void k_wprep(const float* __restrict__ W, const float* __restrict__ s,
                        u16* __restrict__ hi, u16* __restrict__ lo) {
  int idx = blockIdx.x*256 + threadIdx.x;
  int j = idx >> 7, k = idx & 127;
  float v = W[(size_t)k*DD + j];
  if (s) v *= s[k];
  unsigned hb = __float_as_uint(v) & 0xffff0000u;
  float r = v - __uint_as_float(hb);           // exact residual
  hi[idx] = (u16)(hb >> 16);
  lo[idx] = (u16)(__float_as_uint(r) >> 16);
}

// ---------------- exclusive scan (3 pass) ----------------

__global__ void k_scan1(const int* __restrict__ cnt, int* __restrict__ rp, int* __restrict__ bsums) {
  __shared__ int sm[256];
  int tid = threadIdx.x;
  int base = blockIdx.x*1024 + tid*4;
  int4 v = make_int4(0,0,0,0);
  if (base + 3 < NN) v = *(const int4*)(cnt + base);
  else {
    if (base   < NN) v.x = cnt[base];
    if (base+1 < NN) v.y = cnt[base+1];
    if (base+2 < NN) v.z = cnt[base+2];
    if (base+3 < NN) v.w = cnt[base+3];
  }
  int p1 = v.x, p2 = p1 + v.y, p3 = p2 + v.z, tsum = p3 + v.w;
  sm[tid] = tsum; __syncthreads();
  for (int off = 1; off < 256; off <<= 1) {
    int t = (tid >= off) ? sm[tid - off] : 0; __syncthreads();
    sm[tid] += t; __syncthreads();
  }
  int inc = sm[tid];
  int excl = inc - tsum;
  if (base   < NN) rp[base]   = excl;
  if (base+1 < NN) rp[base+1] = excl + p1;
  if (base+2 < NN) rp[base+2] = excl + p2;
  if (base+3 < NN) rp[base+3] = excl + p3;
  if (tid == 255) bsums[blockIdx.x] = inc;
}

__global__ void k_scan2(int* __restrict__ bsums, int nb) {
  __shared__ int sm[256];
  int tid = threadIdx.x;
  int v = (tid < nb) ? bsums[tid] : 0;
  sm[tid] = v; __syncthreads();
  for (int off = 1; off < 256; off <<= 1) {
    int t = (tid >= off) ? sm[tid - off] : 0; __syncthreads();
    sm[tid] += t; __syncthreads();
  }
  if (tid < nb) bsums[tid] = sm[tid] - v;   // exclusive
}

// fused: finalize row pointers + cur + dinv
__global__ void k_scan3(int* __restrict__ rp, const int* __restrict__ bsums,
                        int* __restrict__ cur, const int* __restrict__ cnt,
                        float* __restrict__ dinv) {
  int i = blockIdx.x*256 + threadIdx.x;
  if (i < NN) {
    int val = rp[i] + bsums[i >> 10];
    rp[i] = val; cur[i] = val;
    dinv[i] = rsqrtf((float)(cnt[i] + 1));
  }
  if (i == 0) rp[NN] = NE;
}

__global__ void k_fill(const int* __restrict__ ei, const float* __restrict__ dinv,
                       int* __restrict__ cur, int2* __restrict__ pairs) {
  int e = blockIdx.x*256 + threadIdx.x;
  if (e < NE) {
    int s = ei[e], d = ei[NE + e];
    int pos = atomicAdd(&cur[d], 1);
    float cf = dinv[s] * dinv[d];
    pairs[pos] = make_int2(s, __float_as_int(cf));
  }
}

// ---------------- GEMM: C[N,128] = prelu(A)[N,128] @ W'[128,128] (+ row add) ----------------
// MFMA bf16x3 split-precision: A = Ah+Al, W' = Wh+Wl (pre-split, transposed, BN scale
// folded into W1). acc += Ah*Wh + Ah*Wl + Al*Wh  -> ~fp32 accuracy at MFMA rate.

template<bool FUSE, bool ADDROW>
__global__ __launch_bounds__(256)
void k_gemm(const float* __restrict__ A,
            const u16* __restrict__ wt_hi, const u16* __restrict__ wt_lo,
            float* __restrict__ C,
            const float* __restrict__ tw1, const float* __restrict__ a1p)
{
  __shared__ u16 Bh[128][136];
  __shared__ u16 Bl[128][136];
  const int tid = threadIdx.x;

  // stage Wt hi/lo: 2048 16B chunks each, 8 per thread
  #pragma unroll
  for (int i = 0; i < 8; ++i) {
    int c = tid + i*256;
    int row = c >> 4, slot = c & 15;
    *(uint4*)&Bh[row][slot*8] = ((const uint4*)wt_hi)[c];
    *(uint4*)&Bl[row][slot*8] = ((const uint4*)wt_lo)[c];
  }

  float a1v = 0.f;
  if constexpr (FUSE) a1v = *a1p;

  const int lane = tid & 63;
  const int wv   = tid >> 6;            // wave 0..3
  const int lr   = lane & 15;           // A row within strip / C col within tile
  const int lk   = lane >> 4;           // k sub-block 0..3
  const int r0   = blockIdx.x*128 + wv*32;

  f32x4 acc[2][8];
  #pragma unroll
  for (int s = 0; s < 2; ++s)
    #pragma unroll
    for (int j = 0; j < 8; ++j) acc[s][j] = (f32x4){0.f,0.f,0.f,0.f};

  __syncthreads();

  #pragma unroll
  for (int kc = 0; kc < 4; ++kc) {
    bf16x8 ah[2], al[2];
    #pragma unroll
    for (int s = 0; s < 2; ++s) {
      int r = r0 + s*16 + lr; r = (r < NN) ? r : (NN-1);
      const float* ap = A + (size_t)r*DD + kc*32 + lk*8;
      float4 v0 = *(const float4*)ap;
      float4 v1 = *(const float4*)(ap + 4);
      float vv[8] = {v0.x,v0.y,v0.z,v0.w,v1.x,v1.y,v1.z,v1.w};
      #pragma unroll
      for (int e = 0; e < 8; ++e) {
        float v = vv[e];
        if constexpr (FUSE) v = (v >= 0.f) ? v : a1v*v;
        unsigned hb = __float_as_uint(v) & 0xffff0000u;
        float rres = v - __uint_as_float(hb);    // exact
        ah[s][e] = (short)(hb >> 16);
        al[s][e] = (short)(__float_as_uint(rres) >> 16);
      }
    }
    #pragma unroll
    for (int j = 0; j < 8; ++j) {
      int wrow = j*16 + lr;
      bf16x8 bh = *(const bf16x8*)&Bh[wrow][kc*32 + lk*8];
      bf16x8 bl = *(const bf16x8*)&Bl[wrow][kc*32 + lk*8];
      #pragma unroll
      for (int s = 0; s < 2; ++s) {
        acc[s][j] = __builtin_amdgcn_mfma_f32_16x16x32_bf16(ah[s], bh, acc[s][j], 0, 0, 0);
        acc[s][j] = __builtin_amdgcn_mfma_f32_16x16x32_bf16(ah[s], bl, acc[s][j], 0, 0, 0);
        acc[s][j] = __builtin_amdgcn_mfma_f32_16x16x32_bf16(al[s], bh, acc[s][j], 0, 0, 0);
      }
    }
  }

  float tw[8];
  #pragma unroll
  for (int j = 0; j < 8; ++j) tw[j] = 0.f;
  if constexpr (ADDROW) {
    #pragma unroll
    for (int j = 0; j < 8; ++j) tw[j] = tw1[j*16 + lr];
  }

  // C/D layout (m89): col = lane&15, row = (lane>>4)*4 + reg
  #pragma unroll
  for (int s = 0; s < 2; ++s) {
    #pragma unroll
    for (int g = 0; g < 4; ++g) {
      int row = r0 + s*16 + lk*4 + g;
      if (row < NN) {
        float* cp = C + (size_t)row*DD + lr;
        #pragma unroll
        for (int j = 0; j < 8; ++j) cp[j*16] = acc[s][j][g] + tw[j];
      }
    }
  }
}

// ---------------- aggregation: 8 nodes per wave, interleaved gathers ----------------
// nt-store on out: out is streaming (read back sequentially at most once); keeping it
// out of L3 preserves residency of the 102 MB gather working set (h). Round-3 counters
// showed FETCH = 2x compulsory -> eviction, not concurrency, limits the gather.

template<bool PRELU>
__global__ __launch_bounds__(256)
void k_agg(const float* __restrict__ h, const int* __restrict__ rp,
           const int2* __restrict__ pairs,
           const float* __restrict__ bias, const float* __restrict__ a2p,
           float* __restrict__ out)
{
  const int wave = threadIdx.x >> 6;
  const int lane = threadIdx.x & 63;
  const int nb = (blockIdx.x*4 + wave) * 8;
  if (nb >= NN) return;
  const float2* h2 = (const float2*)h;
  f32x2* o2 = (f32x2*)out;

  int rv = 0;
  if (lane < 9) rv = rp[nb + lane];
  int beg[8], cnt8[8];
  #pragma unroll
  for (int i = 0; i < 8; ++i) {
    int b0 = __builtin_amdgcn_readfirstlane(__shfl(rv, i));
    int b1 = __builtin_amdgcn_readfirstlane(__shfl(rv, i+1));
    beg[i] = b0; cnt8[i] = b1 - b0;
  }

  float2 b = ((const float2*)bias)[lane];
  float a2 = 1.f;
  if constexpr (PRELU) a2 = *a2p;

  float2 acc[8];
  #pragma unroll
  for (int i = 0; i < 8; ++i) {
    float2 self = h2[(size_t)(nb+i)*64 + lane];
    float sc = 1.f / (float)(cnt8[i] + 1);     // dinv^2 exactly
    acc[i].x = sc*self.x + b.x;
    acc[i].y = sc*self.y + b.y;
  }

  int maxc = 0;
  #pragma unroll
  for (int i = 0; i < 8; ++i) maxc = max(maxc, cnt8[i]);

  for (int c = 0; c < maxc; ++c) {
    int2 p[8];
    #pragma unroll
    for (int i = 0; i < 8; ++i)
      if (c < cnt8[i]) p[i] = pairs[beg[i] + c];
    #pragma unroll
    for (int i = 0; i < 8; ++i)
      if (c < cnt8[i]) {
        float2 g = h2[(size_t)p[i].x*64 + lane];
        float cf = __int_as_float(p[i].y);
        acc[i].x += cf*g.x; acc[i].y += cf*g.y;
      }
  }

  #pragma unroll
  for (int i = 0; i < 8; ++i) {
    float ax = acc[i].x, ay = acc[i].y;
    if constexpr (PRELU) {
      ax = (ax >= 0.f) ? ax : a2*ax;
      ay = (ay >= 0.f) ? ay : a2*ay;
    }
    f32x2 o; o[0] = ax; o[1] = ay;
    __builtin_nontemporal_store(o, &o2[(size_t)(nb+i)*64 + lane]);
  }
}

// ---------------- launch ----------------

extern "C" void kernel_launch(void* const* d_in, const int* in_sizes, int n_in,
                              void* d_out, int out_size, void* d_ws, size_t ws_size,
                              hipStream_t stream) {
  const float* x     = (const float*)d_in[0];
  const int*   ei    = (const int*)  d_in[1];
  const float* a1    = (const float*)d_in[2];
  const float* gamma = (const float*)d_in[3];
  const float* beta  = (const float*)d_in[4];
  const float* W1    = (const float*)d_in[5];
  const float* b1    = (const float*)d_in[6];
  const float* a2    = (const float*)d_in[7];
  const float* W2    = (const float*)d_in[8];
  const float* b2    = (const float*)d_in[9];
  float* out = (float*)d_out;

  char* w = (char*)d_ws;
  auto alloc = [&](size_t bytes) { char* p = w; w += (bytes + 255) & ~(size_t)255; return p; };
  float* hbuf  = (float*)alloc((size_t)NN*DD*4);   // 102.4 MB
  float* dinv  = (float*)alloc((size_t)NN*4);
  int*   cnt   = (int*)  alloc((size_t)NN*4);
  int*   rp    = (int*)  alloc((size_t)(NN+1)*4);
  int*   cur   = (int*)  alloc((size_t)NN*4);
  int2*  pairs = (int2*) alloc((size_t)NE*8);
  int*   bsums = (int*)  alloc(256*4);
  float* ssum  = (float*)alloc(128*4);
  float* ssq   = (float*)alloc(128*4);
  float* sarr  = (float*)alloc(128*4);
  float* tarr  = (float*)alloc(128*4);
  float* tw1   = (float*)alloc(128*4);
  u16*   w1h   = (u16*)  alloc(128*128*2);
  u16*   w1l   = (u16*)  alloc(128*128*2);
  u16*   w2h   = (u16*)  alloc(128*128*2);
  u16*   w2l   = (u16*)  alloc(128*128*2);

  const int nblkN = (NN + 255)/256;
  const int nblkE = (NE + 255)/256;
  const int nblkA = NN/32;   // 8 nodes/wave * 4 waves/block

  k_zero  <<<nblkN, 256, 0, stream>>>(cnt, ssum, ssq);
  k_count <<<nblkE, 256, 0, stream>>>(ei, cnt);
  k_stats <<<1024,  256, 0, stream>>>(x, a1, ssum, ssq);
  k_bn_tw1<<<1,     128, 0, stream>>>(ssum, ssq, gamma, beta, W1, sarr, tarr, tw1);
  k_wprep <<<64,    256, 0, stream>>>(W2, nullptr, w2h, w2l);
  k_wprep <<<64,    256, 0, stream>>>(W1, sarr,    w1h, w1l);
  k_scan1 <<<196,   256, 0, stream>>>(cnt, rp, bsums);
  k_scan2 <<<1,     256, 0, stream>>>(bsums, 196);
  k_scan3 <<<nblkN, 256, 0, stream>>>(rp, bsums, cur, cnt, dinv);
  k_fill  <<<nblkE, 256, 0, stream>>>(ei, dinv, cur, pairs);

  k_gemm<true,  true ><<<GT, 256, 0, stream>>>(x,   w1h, w1l, hbuf, tw1, a1);
  k_agg <true >        <<<nblkA, 256, 0, stream>>>(hbuf, rp, pairs, b1, a2, out);
  k_gemm<false, false><<<GT, 256, 0, stream>>>(out, w2h, w2l, hbuf, nullptr, nullptr);
  k_agg <false>        <<<nblkA, 256, 0, stream>>>(hbuf, rp, pairs, b2, nullptr, out);
}

// Round 7
// 503.497 us; speedup vs baseline: 1.1014x; 1.0247x over previous
//
#include <hip/hip_runtime.h>

#define NN 200000
#define NE 600000
#define DD 128
#define GT 1563   // ceil(NN/128) gemm row tiles

constexpr float BN_EPS = 1e-5f;

typedef unsigned short u16;
typedef short bf16x8 __attribute__((ext_vector_type(8)));
typedef float f32x4  __attribute__((ext_vector_type(4)));
typedef float f32x2  __attribute__((ext_vector_type(2)));

// ---------------- init / degree / stats ----------------

__global__ void k_zero(int* __restrict__ cnt, float* __restrict__ ssum, float* __restrict__ ssq) {
  int i = blockIdx.x*256 + threadIdx.x;
  if (i < NN) cnt[i] = 0;
  if (i < DD) { ssum[i] = 0.f; ssq[i] = 0.f; }
}

__global__ void k_count(const int* __restrict__ ei, int* __restrict__ cnt) {
  int e = blockIdx.x*256 + threadIdx.x;
  if (e < NE) atomicAdd(&cnt[ei[NE + e]], 1);
}

// column sums of prelu(x, a1): ssum[c], ssq[c]
__global__ void k_stats(const float* __restrict__ x, const float* __restrict__ a1p,
                        float* __restrict__ ssum, float* __restrict__ ssq) {
  __shared__ float s1[8][128], s2[8][128];
  const int c4 = (threadIdx.x & 31) * 4;
  const int rg = threadIdx.x >> 5;
  float a1 = *a1p;
  float acc1[4] = {0.f,0.f,0.f,0.f}, acc2[4] = {0.f,0.f,0.f,0.f};
  const int stride = gridDim.x * 8;
  for (int r = blockIdx.x*8 + rg; r < NN; r += stride) {
    float4 v = *(const float4*)(x + (size_t)r*DD + c4);
    float vv[4] = {v.x, v.y, v.z, v.w};
    #pragma unroll
    for (int i = 0; i < 4; ++i) {
      float u = vv[i];
      u = (u >= 0.f) ? u : a1*u;
      acc1[i] += u; acc2[i] += u*u;
    }
  }
  *(float4*)&s1[rg][c4] = make_float4(acc1[0], acc1[1], acc1[2], acc1[3]);
  *(float4*)&s2[rg][c4] = make_float4(acc2[0], acc2[1], acc2[2], acc2[3]);
  __syncthreads();
  if (threadIdx.x < 128) {
    int col = threadIdx.x;
    float t1 = 0.f, t2 = 0.f;
    #pragma unroll
    for (int g = 0; g < 8; ++g) { t1 += s1[g][col]; t2 += s2[g][col]; }
    atomicAdd(&ssum[col], t1);
    atomicAdd(&ssq [col], t2);
  }
}

// BN params s,t and tw1[j] = sum_k t[k] * W1[k,j]   (single block, 128 threads)
__global__ void k_bn_tw1(const float* __restrict__ ssum, const float* __restrict__ ssq,
                         const float* __restrict__ gamma, const float* __restrict__ beta,
                         const float* __restrict__ W1,
                         float* __restrict__ sarr, float* __restrict__ tarr,
                         float* __restrict__ tw1) {
  __shared__ float ts[128];
  int j = threadIdx.x;
  float mean = ssum[j] * (1.f/NN);
  float var  = ssq[j] * (1.f/NN) - mean*mean;
  float s = gamma[j] * rsqrtf(var + BN_EPS);
  float t = beta[j] - mean*s;
  sarr[j] = s; tarr[j] = t; ts[j] = t;
  __syncthreads();
  float acc = 0.f;
  #pragma unroll 8
  for (int k = 0; k < 128; ++k) acc += ts[k] * W1[k*DD + j];
  tw1[j] = acc;
}

// W prep: Wt[j][k] = (s ? s[k] : 1) * W[k][j], split into bf16 hi/lo (truncation).
__global__ void k_wprep(const float* __restrict__ W, const float* __restrict__ s,
                        u16* __restrict__ hi, u16* __restrict__ lo) {
  int idx = blockIdx.x*256 + threadIdx.x;
  int j = idx >> 7, k = idx & 127;
  float v = W[(size_t)k*DD + j];
  if (s) v *= s[k];
  unsigned hb = __float_as_uint(v) & 0xffff0000u;
  float r = v - __uint_as_float(hb);           // exact residual
  hi[idx] = (u16)(hb >> 16);
  lo[idx] = (u16)(__float_as_uint(r) >> 16);
}

// ---------------- exclusive scan (3 pass) ----------------

__global__ void k_scan1(const int* __restrict__ cnt, int* __restrict__ rp, int* __restrict__ bsums) {
  __shared__ int sm[256];
  int tid = threadIdx.x;
  int base = blockIdx.x*1024 + tid*4;
  int4 v = make_int4(0,0,0,0);
  if (base + 3 < NN) v = *(const int4*)(cnt + base);
  else {
    if (base   < NN) v.x = cnt[base];
    if (base+1 < NN) v.y = cnt[base+1];
    if (base+2 < NN) v.z = cnt[base+2];
    if (base+3 < NN) v.w = cnt[base+3];
  }
  int p1 = v.x, p2 = p1 + v.y, p3 = p2 + v.z, tsum = p3 + v.w;
  sm[tid] = tsum; __syncthreads();
  for (int off = 1; off < 256; off <<= 1) {
    int t = (tid >= off) ? sm[tid - off] : 0; __syncthreads();
    sm[tid] += t; __syncthreads();
  }
  int inc = sm[tid];
  int excl = inc - tsum;
  if (base   < NN) rp[base]   = excl;
  if (base+1 < NN) rp[base+1] = excl + p1;
  if (base+2 < NN) rp[base+2] = excl + p2;
  if (base+3 < NN) rp[base+3] = excl + p3;
  if (tid == 255) bsums[blockIdx.x] = inc;
}

__global__ void k_scan2(int* __restrict__ bsums, int nb) {
  __shared__ int sm[256];
  int tid = threadIdx.x;
  int v = (tid < nb) ? bsums[tid] : 0;
  sm[tid] = v; __syncthreads();
  for (int off = 1; off < 256; off <<= 1) {
    int t = (tid >= off) ? sm[tid - off] : 0; __syncthreads();
    sm[tid] += t; __syncthreads();
  }
  if (tid < nb) bsums[tid] = sm[tid] - v;   // exclusive
}

__global__ void k_scan3(int* __restrict__ rp, const int* __restrict__ bsums,
                        int* __restrict__ cur, const int* __restrict__ cnt,
                        float* __restrict__ dinv) {
  int i = blockIdx.x*256 + threadIdx.x;
  if (i < NN) {
    int val = rp[i] + bsums[i >> 10];
    rp[i] = val; cur[i] = val;
    dinv[i] = rsqrtf((float)(cnt[i] + 1));
  }
  if (i == 0) rp[NN] = NE;
}

__global__ void k_fill(const int* __restrict__ ei, const float* __restrict__ dinv,
                       int* __restrict__ cur, int2* __restrict__ pairs) {
  int e = blockIdx.x*256 + threadIdx.x;
  if (e < NE) {
    int s = ei[e], d = ei[NE + e];
    int pos = atomicAdd(&cur[d], 1);
    float cf = dinv[s] * dinv[d];
    pairs[pos] = make_int2(s, __float_as_int(cf));
  }
}

// ---------------- GEMM: C[N,128] = prelu(A)[N,128] @ W'[128,128] (+ row add) ----------------
// MFMA bf16x3 split-precision (verified operand/output mapping — k_fagg mirrors it).

template<bool FUSE, bool ADDROW>
__global__ __launch_bounds__(256)
void k_gemm(const float* __restrict__ A,
            const u16* __restrict__ wt_hi, const u16* __restrict__ wt_lo,
            float* __restrict__ C,
            const float* __restrict__ tw1, const float* __restrict__ a1p)
{
  __shared__ u16 Bh[128][136];
  __shared__ u16 Bl[128][136];
  const int tid = threadIdx.x;

  #pragma unroll
  for (int i = 0; i < 8; ++i) {
    int c = tid + i*256;
    int row = c >> 4, slot = c & 15;
    *(uint4*)&Bh[row][slot*8] = ((const uint4*)wt_hi)[c];
    *(uint4*)&Bl[row][slot*8] = ((const uint4*)wt_lo)[c];
  }

  float a1v = 0.f;
  if constexpr (FUSE) a1v = *a1p;

  const int lane = tid & 63;
  const int wv   = tid >> 6;
  const int lr   = lane & 15;
  const int lk   = lane >> 4;
  const int r0   = blockIdx.x*128 + wv*32;

  f32x4 acc[2][8];
  #pragma unroll
  for (int s = 0; s < 2; ++s)
    #pragma unroll
    for (int j = 0; j < 8; ++j) acc[s][j] = (f32x4){0.f,0.f,0.f,0.f};

  __syncthreads();

  #pragma unroll
  for (int kc = 0; kc < 4; ++kc) {
    bf16x8 ah[2], al[2];
    #pragma unroll
    for (int s = 0; s < 2; ++s) {
      int r = r0 + s*16 + lr; r = (r < NN) ? r : (NN-1);
      const float* ap = A + (size_t)r*DD + kc*32 + lk*8;
      float4 v0 = *(const float4*)ap;
      float4 v1 = *(const float4*)(ap + 4);
      float vv[8] = {v0.x,v0.y,v0.z,v0.w,v1.x,v1.y,v1.z,v1.w};
      #pragma unroll
      for (int e = 0; e < 8; ++e) {
        float v = vv[e];
        if constexpr (FUSE) v = (v >= 0.f) ? v : a1v*v;
        unsigned hb = __float_as_uint(v) & 0xffff0000u;
        float rres = v - __uint_as_float(hb);
        ah[s][e] = (short)(hb >> 16);
        al[s][e] = (short)(__float_as_uint(rres) >> 16);
      }
    }
    #pragma unroll
    for (int j = 0; j < 8; ++j) {
      int wrow = j*16 + lr;
      bf16x8 bh = *(const bf16x8*)&Bh[wrow][kc*32 + lk*8];
      bf16x8 bl = *(const bf16x8*)&Bl[wrow][kc*32 + lk*8];
      #pragma unroll
      for (int s = 0; s < 2; ++s) {
        acc[s][j] = __builtin_amdgcn_mfma_f32_16x16x32_bf16(ah[s], bh, acc[s][j], 0, 0, 0);
        acc[s][j] = __builtin_amdgcn_mfma_f32_16x16x32_bf16(ah[s], bl, acc[s][j], 0, 0, 0);
        acc[s][j] = __builtin_amdgcn_mfma_f32_16x16x32_bf16(al[s], bh, acc[s][j], 0, 0, 0);
      }
    }
  }

  float tw[8];
  #pragma unroll
  for (int j = 0; j < 8; ++j) tw[j] = 0.f;
  if constexpr (ADDROW) {
    #pragma unroll
    for (int j = 0; j < 8; ++j) tw[j] = tw1[j*16 + lr];
  }

  #pragma unroll
  for (int s = 0; s < 2; ++s) {
    #pragma unroll
    for (int g = 0; g < 4; ++g) {
      int row = r0 + s*16 + lk*4 + g;
      if (row < NN) {
        float* cp = C + (size_t)row*DD + lr;
        #pragma unroll
        for (int j = 0; j < 8; ++j) cp[j*16] = acc[s][j][g] + tw[j];
      }
    }
  }
}

// ---------------- fused agg1 + prelu(a2) + gemm2 ----------------
// Gather is the verified round-3 structure (wave = 8 nodes, contiguous 512B row
// reads, 8 interleaved chains). Then: +b1, prelu(a2), bf16 hi/lo split, transpose
// through LDS [32][136] u16 (272B stride = structural-floor banking for b128),
// barrier, and each wave computes a 32-col slice of the block's 32x128 output with
// 48 MFMAs (operand/output mapping identical to k_gemm). W2t frags are L2-resident
// (same 128KB for all blocks). Deletes the standalone gemm2's 202MB HBM round-trip.
// NN % 32 == 0 -> no early return (barrier safety).

__global__ __launch_bounds__(256)
void k_fagg(const float* __restrict__ h, const int* __restrict__ rp,
            const int2* __restrict__ pairs,
            const u16* __restrict__ w2h, const u16* __restrict__ w2l,
            const float* __restrict__ b1, const float* __restrict__ a2p,
            float* __restrict__ h2)
{
  __shared__ u16 Ghi[32][136];
  __shared__ u16 Glo[32][136];
  const int wave = threadIdx.x >> 6;
  const int lane = threadIdx.x & 63;
  const int nbB  = blockIdx.x * 32;
  const int nb   = nbB + wave*8;
  const float2* hv = (const float2*)h;

  int rv = 0;
  if (lane < 9) rv = rp[nb + lane];
  int beg[8], cnt8[8];
  #pragma unroll
  for (int i = 0; i < 8; ++i) {
    int b0 = __builtin_amdgcn_readfirstlane(__shfl(rv, i));
    int b1v = __builtin_amdgcn_readfirstlane(__shfl(rv, i+1));
    beg[i] = b0; cnt8[i] = b1v - b0;
  }

  float2 b = ((const float2*)b1)[lane];
  float2 acc[8];
  #pragma unroll
  for (int i = 0; i < 8; ++i) {
    float2 self = hv[(size_t)(nb+i)*64 + lane];
    float sc = 1.f / (float)(cnt8[i] + 1);
    acc[i].x = sc*self.x + b.x;
    acc[i].y = sc*self.y + b.y;
  }

  int maxc = 0;
  #pragma unroll
  for (int i = 0; i < 8; ++i) maxc = max(maxc, cnt8[i]);

  for (int c = 0; c < maxc; ++c) {
    int2 p[8];
    #pragma unroll
    for (int i = 0; i < 8; ++i)
      if (c < cnt8[i]) p[i] = pairs[beg[i] + c];
    #pragma unroll
    for (int i = 0; i < 8; ++i)
      if (c < cnt8[i]) {
        float2 g = hv[(size_t)p[i].x*64 + lane];
        float cf = __int_as_float(p[i].y);
        acc[i].x += cf*g.x; acc[i].y += cf*g.y;
      }
  }

  // prelu(a2) + bf16 hi/lo split -> LDS transpose (lane owns feats 2l,2l+1)
  float a2 = *a2p;
  #pragma unroll
  for (int i = 0; i < 8; ++i) {
    float ax = acc[i].x, ay = acc[i].y;
    ax = (ax >= 0.f) ? ax : a2*ax;
    ay = (ay >= 0.f) ? ay : a2*ay;
    unsigned hx = __float_as_uint(ax) & 0xffff0000u;
    unsigned hy = __float_as_uint(ay) & 0xffff0000u;
    float rx = ax - __uint_as_float(hx);
    float ry = ay - __uint_as_float(hy);
    unsigned hiw = (hx >> 16) | hy;
    unsigned low = (__float_as_uint(rx) >> 16) | (__float_as_uint(ry) & 0xffff0000u);
    int row = wave*8 + i;
    *(unsigned*)&Ghi[row][lane*2] = hiw;
    *(unsigned*)&Glo[row][lane*2] = low;
  }
  __syncthreads();

  // gemm epilogue: rows nbB..nbB+31, cols wave*32..wave*32+31
  const int lr = lane & 15, lk = lane >> 4;
  f32x4 dacc[2][2];
  #pragma unroll
  for (int s = 0; s < 2; ++s)
    #pragma unroll
    for (int t = 0; t < 2; ++t) dacc[s][t] = (f32x4){0.f,0.f,0.f,0.f};

  #pragma unroll
  for (int kc = 0; kc < 4; ++kc) {
    bf16x8 ah0 = *(const bf16x8*)&Ghi[lr]   [kc*32 + lk*8];
    bf16x8 al0 = *(const bf16x8*)&Glo[lr]   [kc*32 + lk*8];
    bf16x8 ah1 = *(const bf16x8*)&Ghi[16+lr][kc*32 + lk*8];
    bf16x8 al1 = *(const bf16x8*)&Glo[16+lr][kc*32 + lk*8];
    #pragma unroll
    for (int t = 0; t < 2; ++t) {
      int wrow = wave*32 + t*16 + lr;
      bf16x8 bh = *(const bf16x8*)(w2h + (size_t)wrow*DD + kc*32 + lk*8);
      bf16x8 bl = *(const bf16x8*)(w2l + (size_t)wrow*DD + kc*32 + lk*8);
      dacc[0][t] = __builtin_amdgcn_mfma_f32_16x16x32_bf16(ah0, bh, dacc[0][t], 0, 0, 0);
      dacc[0][t] = __builtin_amdgcn_mfma_f32_16x16x32_bf16(ah0, bl, dacc[0][t], 0, 0, 0);
      dacc[0][t] = __builtin_amdgcn_mfma_f32_16x16x32_bf16(al0, bh, dacc[0][t], 0, 0, 0);
      dacc[1][t] = __builtin_amdgcn_mfma_f32_16x16x32_bf16(ah1, bh, dacc[1][t], 0, 0, 0);
      dacc[1][t] = __builtin_amdgcn_mfma_f32_16x16x32_bf16(ah1, bl, dacc[1][t], 0, 0, 0);
      dacc[1][t] = __builtin_amdgcn_mfma_f32_16x16x32_bf16(al1, bh, dacc[1][t], 0, 0, 0);
    }
  }

  // D layout: col = lane&15, row = (lane>>4)*4 + reg (m89, same as k_gemm)
  #pragma unroll
  for (int s = 0; s < 2; ++s)
    #pragma unroll
    for (int t = 0; t < 2; ++t)
      #pragma unroll
      for (int g = 0; g < 4; ++g) {
        int row = nbB + s*16 + lk*4 + g;
        h2[(size_t)row*DD + wave*32 + t*16 + lr] = dacc[s][t][g];
      }
}

// ---------------- aggregation: 8 nodes per wave, interleaved gathers ----------------

template<bool PRELU>
__global__ __launch_bounds__(256)
void k_agg(const float* __restrict__ h, const int* __restrict__ rp,
           const int2* __restrict__ pairs,
           const float* __restrict__ bias, const float* __restrict__ a2p,
           float* __restrict__ out)
{
  const int wave = threadIdx.x >> 6;
  const int lane = threadIdx.x & 63;
  const int nb = (blockIdx.x*4 + wave) * 8;
  if (nb >= NN) return;
  const float2* h2 = (const float2*)h;
  f32x2* o2 = (f32x2*)out;

  int rv = 0;
  if (lane < 9) rv = rp[nb + lane];
  int beg[8], cnt8[8];
  #pragma unroll
  for (int i = 0; i < 8; ++i) {
    int b0 = __builtin_amdgcn_readfirstlane(__shfl(rv, i));
    int b1 = __builtin_amdgcn_readfirstlane(__shfl(rv, i+1));
    beg[i] = b0; cnt8[i] = b1 - b0;
  }

  float2 b = ((const float2*)bias)[lane];
  float a2 = 1.f;
  if constexpr (PRELU) a2 = *a2p;

  float2 acc[8];
  #pragma unroll
  for (int i = 0; i < 8; ++i) {
    float2 self = h2[(size_t)(nb+i)*64 + lane];
    float sc = 1.f / (float)(cnt8[i] + 1);
    acc[i].x = sc*self.x + b.x;
    acc[i].y = sc*self.y + b.y;
  }

  int maxc = 0;
  #pragma unroll
  for (int i = 0; i < 8; ++i) maxc = max(maxc, cnt8[i]);

  for (int c = 0; c < maxc; ++c) {
    int2 p[8];
    #pragma unroll
    for (int i = 0; i < 8; ++i)
      if (c < cnt8[i]) p[i] = pairs[beg[i] + c];
    #pragma unroll
    for (int i = 0; i < 8; ++i)
      if (c < cnt8[i]) {
        float2 g = h2[(size_t)p[i].x*64 + lane];
        float cf = __int_as_float(p[i].y);
        acc[i].x += cf*g.x; acc[i].y += cf*g.y;
      }
  }

  #pragma unroll
  for (int i = 0; i < 8; ++i) {
    float ax = acc[i].x, ay = acc[i].y;
    if constexpr (PRELU) {
      ax = (ax >= 0.f) ? ax : a2*ax;
      ay = (ay >= 0.f) ? ay : a2*ay;
    }
    f32x2 o; o[0] = ax; o[1] = ay;
    __builtin_nontemporal_store(o, &o2[(size_t)(nb+i)*64 + lane]);
  }
}

// ---------------- launch ----------------

extern "C" void kernel_launch(void* const* d_in, const int* in_sizes, int n_in,
                              void* d_out, int out_size, void* d_ws, size_t ws_size,
                              hipStream_t stream) {
  const float* x     = (const float*)d_in[0];
  const int*   ei    = (const int*)  d_in[1];
  const float* a1    = (const float*)d_in[2];
  const float* gamma = (const float*)d_in[3];
  const float* beta  = (const float*)d_in[4];
  const float* W1    = (const float*)d_in[5];
  const float* b1    = (const float*)d_in[6];
  const float* a2    = (const float*)d_in[7];
  const float* W2    = (const float*)d_in[8];
  const float* b2    = (const float*)d_in[9];
  float* out = (float*)d_out;

  char* w = (char*)d_ws;
  auto alloc = [&](size_t bytes) { char* p = w; w += (bytes + 255) & ~(size_t)255; return p; };
  float* hbuf  = (float*)alloc((size_t)NN*DD*4);   // 102.4 MB
  float* dinv  = (float*)alloc((size_t)NN*4);
  int*   cnt   = (int*)  alloc((size_t)NN*4);
  int*   rp    = (int*)  alloc((size_t)(NN+1)*4);
  int*   cur   = (int*)  alloc((size_t)NN*4);
  int2*  pairs = (int2*) alloc((size_t)NE*8);
  int*   bsums = (int*)  alloc(256*4);
  float* ssum  = (float*)alloc(128*4);
  float* ssq   = (float*)alloc(128*4);
  float* sarr  = (float*)alloc(128*4);
  float* tarr  = (float*)alloc(128*4);
  float* tw1   = (float*)alloc(128*4);
  u16*   w1h   = (u16*)  alloc(128*128*2);
  u16*   w1l   = (u16*)  alloc(128*128*2);
  u16*   w2h   = (u16*)  alloc(128*128*2);
  u16*   w2l   = (u16*)  alloc(128*128*2);
  float* hbuf2 = (float*)alloc((size_t)NN*DD*4);   // 102.4 MB (fused path only)
  const bool fused = ((size_t)(w - (char*)d_ws) <= ws_size);

  const int nblkN = (NN + 255)/256;
  const int nblkE = (NE + 255)/256;
  const int nblkA = NN/32;   // 8 nodes/wave * 4 waves/block
  const int nblkF = NN/32;   // k_fagg: 32 rows/block

  k_zero  <<<nblkN, 256, 0, stream>>>(cnt, ssum, ssq);
  k_count <<<nblkE, 256, 0, stream>>>(ei, cnt);
  k_stats <<<1024,  256, 0, stream>>>(x, a1, ssum, ssq);
  k_bn_tw1<<<1,     128, 0, stream>>>(ssum, ssq, gamma, beta, W1, sarr, tarr, tw1);
  k_wprep <<<64,    256, 0, stream>>>(W2, nullptr, w2h, w2l);
  k_wprep <<<64,    256, 0, stream>>>(W1, sarr,    w1h, w1l);
  k_scan1 <<<196,   256, 0, stream>>>(cnt, rp, bsums);
  k_scan2 <<<1,     256, 0, stream>>>(bsums, 196);
  k_scan3 <<<nblkN, 256, 0, stream>>>(rp, bsums, cur, cnt, dinv);
  k_fill  <<<nblkE, 256, 0, stream>>>(ei, dinv, cur, pairs);

  k_gemm<true, true><<<GT, 256, 0, stream>>>(x, w1h, w1l, hbuf, tw1, a1);
  if (fused) {
    // agg1 + prelu(a2) + gemm2 fused: hbuf -> hbuf2 (layer-2 pre-agg activations)
    k_fagg<<<nblkF, 256, 0, stream>>>(hbuf, rp, pairs, w2h, w2l, b1, a2, hbuf2);
    k_agg<false><<<nblkA, 256, 0, stream>>>(hbuf2, rp, pairs, b2, nullptr, out);
  } else {
    k_agg<true >         <<<nblkA, 256, 0, stream>>>(hbuf, rp, pairs, b1, a2, out);
    k_gemm<false, false><<<GT, 256, 0, stream>>>(out, w2h, w2l, hbuf, nullptr, nullptr);
    k_agg<false>         <<<nblkA, 256, 0, stream>>>(hbuf, rp, pairs, b2, nullptr, out);
  }
}